// Round 9
// baseline (94.351 us; speedup 1.0000x reference)
//
#include <hip/hip_runtime.h>

#define TOKENS 16384
#define HDIM   4096
#define NPARTS 8
#define KPW    (HDIM / NPARTS)      // 512 k per K-part
#define NCHK   (KPW / 32)           // 16 chunks per part
#define CHU    768                  // int4 units per chunk (4nt x 3 planes x 64)

typedef __attribute__((ext_vector_type(8))) short bf16x8;
typedef __attribute__((ext_vector_type(4))) float f32x4;

union PKU { unsigned int u[4]; int4 i4; bf16x8 v; };

__device__ __forceinline__ float4 L(const float* p) {
  return *reinterpret_cast<const float4*>(p);
}

// Exact 3-way bf16 split of 8 fp32: x = h + m + l (+O(2^-27) truncation)
__device__ __forceinline__ void split8(const float4 a, const float4 b,
                                       int4& h4, int4& m4, int4& l4) {
  const float e[8] = {a.x, a.y, a.z, a.w, b.x, b.y, b.z, b.w};
  unsigned int hb[8], mb[8], lb[8];
#pragma unroll
  for (int i = 0; i < 8; ++i) {
    const unsigned int xb = __float_as_uint(e[i]);
    hb[i] = xb & 0xFFFF0000u;
    const float r = e[i] - __uint_as_float(hb[i]);
    const unsigned int rb = __float_as_uint(r);
    mb[i] = rb & 0xFFFF0000u;
    const float r2 = r - __uint_as_float(mb[i]);
    lb[i] = __float_as_uint(r2);
  }
  PKU h, m, l;
#pragma unroll
  for (int j = 0; j < 4; ++j) {
    h.u[j] = (hb[2*j] >> 16) | (hb[2*j+1] & 0xFFFF0000u);
    m.u[j] = (mb[2*j] >> 16) | (mb[2*j+1] & 0xFFFF0000u);
    l.u[j] = (lb[2*j] >> 16) | (lb[2*j+1] & 0xFFFF0000u);
  }
  h4 = h.i4; m4 = m.i4; l4 = l.i4;
}

__device__ __forceinline__ bf16x8 asbf(const int4 x) { PKU u; u.i4 = x; return u.v; }

#define MFMA6(ACC, AH, AM, AL, BH, BM, BL)                                     \
  ACC = __builtin_amdgcn_mfma_f32_16x16x32_bf16(AH, BH, ACC, 0, 0, 0);         \
  ACC = __builtin_amdgcn_mfma_f32_16x16x32_bf16(AM, BH, ACC, 0, 0, 0);         \
  ACC = __builtin_amdgcn_mfma_f32_16x16x32_bf16(AH, BM, ACC, 0, 0, 0);         \
  ACC = __builtin_amdgcn_mfma_f32_16x16x32_bf16(AL, BH, ACC, 0, 0, 0);         \
  ACC = __builtin_amdgcn_mfma_f32_16x16x32_bf16(AH, BL, ACC, 0, 0, 0);         \
  ACC = __builtin_amdgcn_mfma_f32_16x16x32_bf16(AM, BM, ACC, 0, 0, 0);

__device__ __forceinline__ void load_lds16(const float* g, float* l) {
  __builtin_amdgcn_global_load_lds(
      (const __attribute__((address_space(1))) void*)g,
      (__attribute__((address_space(3))) void*)l, 16, 0, 0);
}

// Pre-split gate into bf16 h/m/l planes, chunk-contiguous:
// wsB[(part*16+ch)*768 + (nt*3+plane)*64 + lane]. Block 0 also zeros accum
// (plain stores; stream order makes them visible to later kernels).
__global__ void prep_gate_kernel(const float* __restrict__ gate,
                                 int4* __restrict__ wsB,
                                 float* __restrict__ accum) {
  const int c    = blockIdx.x;          // part*16 + chunk
  const int tid  = threadIdx.x;         // 256
  if (c == 0 && tid < 128) accum[tid] = 0.f;
  const int lane = tid & 63, nt = tid >> 6;
  const int col16 = lane & 15, kq = lane >> 4;
  const int k = (c >> 4) * KPW + (c & 15) * 32 + kq * 8;
  const float* gp = gate + (size_t)(nt * 16 + col16) * HDIM + k;
  int4 h, m, l;
  split8(L(gp), L(gp + 4), h, m, l);
  int4* dst = wsB + (size_t)c * CHU + nt * 3 * 64 + lane;
  dst[0] = h; dst[64] = m; dst[128] = l;
}

// 256-thread blocks (4 waves), 128 tokens/block, 1024 blocks -> 4 blocks/CU.
__global__ __launch_bounds__(256, 4)
void router_gemm_kernel(const float* __restrict__ hidden,
                        const int4* __restrict__ wsB,
                        float* __restrict__ pw) {
  __shared__ int4 bbuf[2][CHU];         // 24 KB double-buffered B planes

  const int tid   = threadIdx.x;
  const int lane  = tid & 63;
  const int wave  = tid >> 6;           // 0..3
  const int col16 = lane & 15;
  const int kq    = lane >> 4;
  const int part  = blockIdx.x & 7;     // fast dim -> pinned XCD for B slice
  const int tg    = blockIdx.x >> 3;
  const int tok0  = tg * 128 + wave * 32;

  const float* aP0 = hidden + (size_t)(tok0 + col16) * HDIM + part * KPW + kq * 8;
  const float* aP1 = aP0 + (size_t)16 * HDIM;
  const int4* wsrc = wsB + (size_t)part * NCHK * CHU;

  f32x4 acc0[4], acc1[4];
#pragma unroll
  for (int nt = 0; nt < 4; ++nt) {
    acc0[nt] = (f32x4){0.f, 0.f, 0.f, 0.f};
    acc1[nt] = (f32x4){0.f, 0.f, 0.f, 0.f};
  }

  // 768 units / 256 threads = 3 per thread; dest = wave-uniform base + lane*16.
  auto stage = [&](int c, int bi) {
    const int4* s = wsrc + c * CHU;
#pragma unroll
    for (int t = 0; t < 3; ++t)
      load_lds16((const float*)(s + t * 256 + wave * 64 + lane),
                 (float*)&bbuf[bi][t * 256 + wave * 64]);
  };

  float4 a00 = L(aP0),     a01 = L(aP0 + 4);
  float4 a10 = L(aP1),     a11 = L(aP1 + 4);
  stage(0, 0);
  __syncthreads();                       // drains vmcnt: buf0 + A(0) ready

#pragma unroll 1
  for (int c = 0; c < NCHK; ++c) {
    const int cur = c & 1;
    if (c + 1 < NCHK) stage(c + 1, cur ^ 1);
    float4 n00, n01, n10, n11;
    if (c + 1 < NCHK) {
      const int ko = (c + 1) * 32;
      n00 = L(aP0 + ko); n01 = L(aP0 + ko + 4);
      n10 = L(aP1 + ko); n11 = L(aP1 + ko + 4);
    }
    int4 h4, m4, l4;
    split8(a00, a01, h4, m4, l4);
    const bf16x8 a0h = asbf(h4), a0m = asbf(m4), a0l = asbf(l4);
    split8(a10, a11, h4, m4, l4);
    const bf16x8 a1h = asbf(h4), a1m = asbf(m4), a1l = asbf(l4);
#pragma unroll
    for (int nt = 0; nt < 4; ++nt) {
      const bf16x8 bh = asbf(bbuf[cur][(nt * 3 + 0) * 64 + lane]);
      const bf16x8 bm = asbf(bbuf[cur][(nt * 3 + 1) * 64 + lane]);
      const bf16x8 bl = asbf(bbuf[cur][(nt * 3 + 2) * 64 + lane]);
      MFMA6(acc0[nt], a0h, a0m, a0l, bh, bm, bl);
      MFMA6(acc1[nt], a1h, a1m, a1l, bh, bm, bl);
    }
    __syncthreads();                     // buf[cur] consumed; stage(c+1) landed
    a00 = n00; a01 = n01; a10 = n10; a11 = n11;
  }

  // partials[part][tok][e]
  float* prow = pw + (size_t)part * TOKENS * 64;
#pragma unroll
  for (int f = 0; f < 2; ++f)
#pragma unroll
    for (int nt = 0; nt < 4; ++nt)
#pragma unroll
      for (int r = 0; r < 4; ++r) {
        const int tok = tok0 + f * 16 + kq * 4 + r;
        prow[(size_t)tok * 64 + nt * 16 + col16] = f ? acc1[nt][r] : acc0[nt][r];
      }
}

__global__ __launch_bounds__(256, 4)
void router_top2_kernel(const float* __restrict__ pw,
                        float* __restrict__ out,
                        float* __restrict__ accum) {
  __shared__ float red[2][4][4][16];     // [psum/cnt][wave][slice][16]

  const int tid  = threadIdx.x;
  const int lane = tid & 63, wave = tid >> 6;
  const int tok  = blockIdx.x * 64 + wave * 16 + (lane >> 2);
  const int sl   = lane & 3;             // expert slice: e in [sl*16, sl*16+16)

  f32x4 s[4];
#pragma unroll
  for (int q = 0; q < 4; ++q) s[q] = (f32x4){0.f, 0.f, 0.f, 0.f};
#pragma unroll
  for (int p = 0; p < NPARTS; ++p) {
    const float* b = pw + ((size_t)p * TOKENS + tok) * 64 + sl * 16;
#pragma unroll
    for (int q = 0; q < 4; ++q) {
      const float4 v = L(b + q * 4);
      s[q][0] += v.x; s[q][1] += v.y; s[q][2] += v.z; s[q][3] += v.w;
    }
  }

  // in-lane top-2 over 16 experts, ascending index (tie -> lower)
  float v1 = s[0][0]; int i1 = sl * 16;
  float v2 = -3.4e38f; int i2 = 1 << 30;
#pragma unroll
  for (int q = 0; q < 4; ++q)
#pragma unroll
    for (int j = 0; j < 4; ++j) {
      if (q == 0 && j == 0) continue;
      const float v = s[q][j]; const int ix = sl * 16 + q * 4 + j;
      if (v > v1)      { v2 = v1; i2 = i1; v1 = v; i1 = ix; }
      else if (v > v2) { v2 = v;  i2 = ix; }
    }
  // merge across the 4 slice-lanes of this token
#pragma unroll
  for (int m = 1; m < 4; m <<= 1) {
    const float ov1 = __shfl_xor(v1, m, 64); const int oi1 = __shfl_xor(i1, m, 64);
    const float ov2 = __shfl_xor(v2, m, 64); const int oi2 = __shfl_xor(i2, m, 64);
    const bool  ob  = (ov1 > v1) || (ov1 == v1 && oi1 < i1);
    const float lv  = ob ? v1  : ov1;  const int li = ob ? i1  : oi1;
    const float rv  = ob ? ov2 : v2;   const int ri = ob ? oi2 : i2;
    v1 = ob ? ov1 : v1; i1 = ob ? oi1 : i1;
    const bool  ab  = (lv > rv) || (lv == rv && li < ri);
    v2 = ab ? lv : rv;  i2 = ab ? li : ri;
  }
  // full softmax over 64 experts (v1 = true max in all 4 lanes)
  float el[16]; float ls = 0.f;
#pragma unroll
  for (int q = 0; q < 4; ++q)
#pragma unroll
    for (int j = 0; j < 4; ++j) { el[q*4+j] = expf(s[q][j] - v1); ls += el[q*4+j]; }
#pragma unroll
  for (int m = 1; m < 4; m <<= 1) ls += __shfl_xor(ls, m, 64);
  const float inv = 1.f / ls;

  float psum[16], cnt[16];
#pragma unroll
  for (int j = 0; j < 16; ++j) {
    psum[j] = el[j] * inv;
    const int ix = sl * 16 + j;
    cnt[j] = (float)((i1 == ix) + (i2 == ix));
  }

  if (sl == 0) {
    const float e2 = expf(v2 - v1);
    const float w1 = 1.f / (1.f + e2);
    out[tok * 2 + 0] = w1;
    out[tok * 2 + 1] = e2 * w1;
    out[(size_t)TOKENS * 2 + tok * 2 + 0] = (float)i1;
    out[(size_t)TOKENS * 2 + tok * 2 + 1] = (float)i2;
  }

  // per-expert stats: reduce over the 16 tokens of this wave (stride-4 lanes)
#pragma unroll
  for (int m = 4; m < 64; m <<= 1)
#pragma unroll
    for (int j = 0; j < 16; ++j) {
      psum[j] += __shfl_xor(psum[j], m, 64);
      cnt[j]  += __shfl_xor(cnt[j], m, 64);
    }
  if (lane < 4) {
#pragma unroll
    for (int j = 0; j < 16; ++j) {
      red[0][wave][sl][j] = psum[j];
      red[1][wave][sl][j] = cnt[j];
    }
  }
  __syncthreads();
  if (tid < 64) {
    const int sl2 = tid >> 4, j2 = tid & 15;
    float ps = 0.f, cs = 0.f;
#pragma unroll
    for (int w = 0; w < 4; ++w) { ps += red[0][w][sl2][j2]; cs += red[1][w][sl2][j2]; }
    atomicAdd(&accum[sl2 * 16 + j2], ps);
    atomicAdd(&accum[64 + sl2 * 16 + j2], cs);
  }
}

__global__ void router_loss_kernel(const float* __restrict__ accum,
                                   float* __restrict__ out) {
  const int l = threadIdx.x;  // 64 threads
  float term = accum[l] * accum[64 + l];   // P_sum_e * count_e
#pragma unroll
  for (int m = 1; m < 64; m <<= 1) term += __shfl_xor(term, m, 64);
  if (l == 0) {
    const float invN = 1.f / (float)TOKENS;
    out[(size_t)TOKENS * 4] = 0.01f * 64.f * term * invN * invN;
  }
}

extern "C" void kernel_launch(void* const* d_in, const int* in_sizes, int n_in,
                              void* d_out, int out_size, void* d_ws, size_t ws_size,
                              hipStream_t stream) {
  const float* hidden = (const float*)d_in[0];  // [4,4096,4096] f32
  const float* gate   = (const float*)d_in[1];  // [64,4096] f32
  float* out   = (float*)d_out;                 // 32768 w + 32768 idx + 1 loss

  float* accum = (float*)d_ws;                                   // 128 f32
  int4*  wsB   = (int4*)((char*)d_ws + 1024);                    // 1.5 MB planes
  float* pw    = (float*)((char*)d_ws + 1024 + 1572864);         // 33.5 MB partials

  prep_gate_kernel<<<NPARTS * NCHK, 256, 0, stream>>>(gate, wsB, accum);
  router_gemm_kernel<<<(TOKENS / 128) * NPARTS, 256, 0, stream>>>(hidden, wsB, pw);
  router_top2_kernel<<<TOKENS / 64, 256, 0, stream>>>(pw, out, accum);
  router_loss_kernel<<<1, 64, 0, stream>>>(accum, out);
}

// Round 10
// 86.486 us; speedup vs baseline: 1.0909x; 1.0909x over previous
//
#include <hip/hip_runtime.h>

#define TOKENS 16384
#define HDIM   4096
#define NPARTS 8
#define KPW    (HDIM / NPARTS)      // 512 k per K-part
#define NCHK   (KPW / 32)           // 16 chunks per part
#define CHU    768                  // int4 units per chunk (4nt x 3 planes x 64)

typedef __attribute__((ext_vector_type(8))) short bf16x8;
typedef __attribute__((ext_vector_type(4))) float f32x4;

union PKU { unsigned int u[4]; int4 i4; bf16x8 v; };

__device__ __forceinline__ float4 L(const float* p) {
  return *reinterpret_cast<const float4*>(p);
}

// Exact 3-way bf16 split of 8 fp32: x = h + m + l (+O(2^-27) truncation)
__device__ __forceinline__ void split8(const float4 a, const float4 b,
                                       int4& h4, int4& m4, int4& l4) {
  const float e[8] = {a.x, a.y, a.z, a.w, b.x, b.y, b.z, b.w};
  unsigned int hb[8], mb[8], lb[8];
#pragma unroll
  for (int i = 0; i < 8; ++i) {
    const unsigned int xb = __float_as_uint(e[i]);
    hb[i] = xb & 0xFFFF0000u;
    const float r = e[i] - __uint_as_float(hb[i]);
    const unsigned int rb = __float_as_uint(r);
    mb[i] = rb & 0xFFFF0000u;
    const float r2 = r - __uint_as_float(mb[i]);
    lb[i] = __float_as_uint(r2);
  }
  PKU h, m, l;
#pragma unroll
  for (int j = 0; j < 4; ++j) {
    h.u[j] = (hb[2*j] >> 16) | (hb[2*j+1] & 0xFFFF0000u);
    m.u[j] = (mb[2*j] >> 16) | (mb[2*j+1] & 0xFFFF0000u);
    l.u[j] = (lb[2*j] >> 16) | (lb[2*j+1] & 0xFFFF0000u);
  }
  h4 = h.i4; m4 = m.i4; l4 = l.i4;
}

__device__ __forceinline__ bf16x8 asbf(const int4 x) { PKU u; u.i4 = x; return u.v; }

#define MFMA6(ACC, AH, AM, AL, BH, BM, BL)                                     \
  ACC = __builtin_amdgcn_mfma_f32_16x16x32_bf16(AH, BH, ACC, 0, 0, 0);         \
  ACC = __builtin_amdgcn_mfma_f32_16x16x32_bf16(AM, BH, ACC, 0, 0, 0);         \
  ACC = __builtin_amdgcn_mfma_f32_16x16x32_bf16(AH, BM, ACC, 0, 0, 0);         \
  ACC = __builtin_amdgcn_mfma_f32_16x16x32_bf16(AL, BH, ACC, 0, 0, 0);         \
  ACC = __builtin_amdgcn_mfma_f32_16x16x32_bf16(AH, BL, ACC, 0, 0, 0);         \
  ACC = __builtin_amdgcn_mfma_f32_16x16x32_bf16(AM, BM, ACC, 0, 0, 0);

// 512 threads (8 waves), 256 tokens/block, grid 512. Waves 0-3 also split the
// gate slice into bf16 h/m/l planes inline (load c+2 early, write c+1 late).
__global__ __launch_bounds__(512, 4)
void router_gemm_kernel(const float* __restrict__ hidden,
                        const float* __restrict__ gate,
                        float* __restrict__ pw,
                        float* __restrict__ accum) {
  __shared__ int4 bbuf[2][CHU];         // 24 KB double-buffered B planes

  const int tid   = threadIdx.x;
  const int lane  = tid & 63;
  const int wave  = tid >> 6;
  const int col16 = lane & 15;
  const int kq    = lane >> 4;
  const int part  = blockIdx.x & 7;     // fast dim -> pinned XCD for B slice
  const int tg    = blockIdx.x >> 3;
  const int tok0  = tg * 256 + wave * 32;

  if (blockIdx.x == 0 && tid < 128) accum[tid] = 0.f;  // plain stores; stream order

  const float* aP0 = hidden + (size_t)(tok0 + col16) * HDIM + part * KPW + kq * 8;
  const float* aP1 = aP0 + (size_t)16 * HDIM;
  // staging source (valid for waves 0-3): gate row snt*16+col16, k = kq*8..
  const int snt = wave & 3;
  const float* gB = gate + (size_t)(snt * 16 + col16) * HDIM + part * KPW + kq * 8;
  const bool stager = (tid < 256);

  f32x4 acc0[4], acc1[4];
#pragma unroll
  for (int nt = 0; nt < 4; ++nt) {
    acc0[nt] = (f32x4){0.f, 0.f, 0.f, 0.f};
    acc1[nt] = (f32x4){0.f, 0.f, 0.f, 0.f};
  }

  // ---- prologue: split chunk 0 into buf0; prefetch gate chunk 1; A(0) ----
  if (stager) {
    int4 h, m, l;
    split8(L(gB), L(gB + 4), h, m, l);
    int4* d = &bbuf[0][snt * 3 * 64 + lane];
    d[0] = h; d[64] = m; d[128] = l;
  }
  float4 g0, g1;
  if (stager) { g0 = L(gB + 32); g1 = L(gB + 36); }
  float4 a00 = L(aP0), a01 = L(aP0 + 4);
  float4 a10 = L(aP1), a11 = L(aP1 + 4);
  __syncthreads();                       // buf0 + A(0) ready

#pragma unroll 1
  for (int c = 0; c < NCHK; ++c) {
    const int cur = c & 1;
    float4 n00, n01, n10, n11;
    if (c + 1 < NCHK) {                  // A prefetch (issue early)
      const int ko = (c + 1) * 32;
      n00 = L(aP0 + ko); n01 = L(aP0 + ko + 4);
      n10 = L(aP1 + ko); n11 = L(aP1 + ko + 4);
    }
    int4 h4, m4, l4;
    split8(a00, a01, h4, m4, l4);
    const bf16x8 a0h = asbf(h4), a0m = asbf(m4), a0l = asbf(l4);
    split8(a10, a11, h4, m4, l4);
    const bf16x8 a1h = asbf(h4), a1m = asbf(m4), a1l = asbf(l4);
#pragma unroll
    for (int nt = 0; nt < 4; ++nt) {
      const bf16x8 bh = asbf(bbuf[cur][(nt * 3 + 0) * 64 + lane]);
      const bf16x8 bm = asbf(bbuf[cur][(nt * 3 + 1) * 64 + lane]);
      const bf16x8 bl = asbf(bbuf[cur][(nt * 3 + 2) * 64 + lane]);
      MFMA6(acc0[nt], a0h, a0m, a0l, bh, bm, bl);
      MFMA6(acc1[nt], a1h, a1m, a1l, bh, bm, bl);
    }
    // write-late: split gate(c+1) (loaded a chunk ago) into the other buffer,
    // then immediately issue gate(c+2) loads so they land during next chunk.
    if (c + 1 < NCHK && stager) {
      int4 h, m, l;
      split8(g0, g1, h, m, l);
      int4* d = &bbuf[cur ^ 1][snt * 3 * 64 + lane];
      d[0] = h; d[64] = m; d[128] = l;
      if (c + 2 < NCHK) {
        const int go = (c + 2) * 32;
        g0 = L(gB + go); g1 = L(gB + go + 4);
      }
    }
    __syncthreads();                     // buf[cur] consumed; c+1 planes landed
    a00 = n00; a01 = n01; a10 = n10; a11 = n11;
  }

  // partials[part][tok][e]
  float* prow = pw + (size_t)part * TOKENS * 64;
#pragma unroll
  for (int f = 0; f < 2; ++f)
#pragma unroll
    for (int nt = 0; nt < 4; ++nt)
#pragma unroll
      for (int r = 0; r < 4; ++r) {
        const int tok = tok0 + f * 16 + kq * 4 + r;
        prow[(size_t)tok * 64 + nt * 16 + col16] = f ? acc1[nt][r] : acc0[nt][r];
      }
}

__global__ __launch_bounds__(256, 4)
void router_top2_kernel(const float* __restrict__ pw,
                        float* __restrict__ out,
                        float* __restrict__ accum) {
  __shared__ float red[2][4][4][16];     // [psum/cnt][wave][slice][16]

  const int tid  = threadIdx.x;
  const int lane = tid & 63, wave = tid >> 6;
  const int tok  = blockIdx.x * 64 + wave * 16 + (lane >> 2);
  const int sl   = lane & 3;             // expert slice: e in [sl*16, sl*16+16)

  f32x4 s[4];
#pragma unroll
  for (int q = 0; q < 4; ++q) s[q] = (f32x4){0.f, 0.f, 0.f, 0.f};
#pragma unroll
  for (int p = 0; p < NPARTS; ++p) {
    const float* b = pw + ((size_t)p * TOKENS + tok) * 64 + sl * 16;
#pragma unroll
    for (int q = 0; q < 4; ++q) {
      const float4 v = L(b + q * 4);
      s[q][0] += v.x; s[q][1] += v.y; s[q][2] += v.z; s[q][3] += v.w;
    }
  }

  // in-lane top-2 over 16 experts, ascending index (tie -> lower)
  float v1 = s[0][0]; int i1 = sl * 16;
  float v2 = -3.4e38f; int i2 = 1 << 30;
#pragma unroll
  for (int q = 0; q < 4; ++q)
#pragma unroll
    for (int j = 0; j < 4; ++j) {
      if (q == 0 && j == 0) continue;
      const float v = s[q][j]; const int ix = sl * 16 + q * 4 + j;
      if (v > v1)      { v2 = v1; i2 = i1; v1 = v; i1 = ix; }
      else if (v > v2) { v2 = v;  i2 = ix; }
    }
  // merge across the 4 slice-lanes of this token
#pragma unroll
  for (int m = 1; m < 4; m <<= 1) {
    const float ov1 = __shfl_xor(v1, m, 64); const int oi1 = __shfl_xor(i1, m, 64);
    const float ov2 = __shfl_xor(v2, m, 64); const int oi2 = __shfl_xor(i2, m, 64);
    const bool  ob  = (ov1 > v1) || (ov1 == v1 && oi1 < i1);
    const float lv  = ob ? v1  : ov1;  const int li = ob ? i1  : oi1;
    const float rv  = ob ? ov2 : v2;   const int ri = ob ? oi2 : i2;
    v1 = ob ? ov1 : v1; i1 = ob ? oi1 : i1;
    const bool  ab  = (lv > rv) || (lv == rv && li < ri);
    v2 = ab ? lv : rv;  i2 = ab ? li : ri;
  }
  // full softmax over 64 experts (v1 = true max in all 4 lanes)
  float el[16]; float ls = 0.f;
#pragma unroll
  for (int q = 0; q < 4; ++q)
#pragma unroll
    for (int j = 0; j < 4; ++j) { el[q*4+j] = expf(s[q][j] - v1); ls += el[q*4+j]; }
#pragma unroll
  for (int m = 1; m < 4; m <<= 1) ls += __shfl_xor(ls, m, 64);
  const float inv = 1.f / ls;

  float psum[16], cnt[16];
#pragma unroll
  for (int j = 0; j < 16; ++j) {
    psum[j] = el[j] * inv;
    const int ix = sl * 16 + j;
    cnt[j] = (float)((i1 == ix) + (i2 == ix));
  }

  if (sl == 0) {
    const float e2 = expf(v2 - v1);
    const float w1 = 1.f / (1.f + e2);
    out[tok * 2 + 0] = w1;
    out[tok * 2 + 1] = e2 * w1;
    out[(size_t)TOKENS * 2 + tok * 2 + 0] = (float)i1;
    out[(size_t)TOKENS * 2 + tok * 2 + 1] = (float)i2;
  }

  // per-expert stats: reduce over the 16 tokens of this wave (stride-4 lanes)
#pragma unroll
  for (int m = 4; m < 64; m <<= 1)
#pragma unroll
    for (int j = 0; j < 16; ++j) {
      psum[j] += __shfl_xor(psum[j], m, 64);
      cnt[j]  += __shfl_xor(cnt[j], m, 64);
    }
  if (lane < 4) {
#pragma unroll
    for (int j = 0; j < 16; ++j) {
      red[0][wave][sl][j] = psum[j];
      red[1][wave][sl][j] = cnt[j];
    }
  }
  __syncthreads();
  if (tid < 64) {
    const int sl2 = tid >> 4, j2 = tid & 15;
    float ps = 0.f, cs = 0.f;
#pragma unroll
    for (int w = 0; w < 4; ++w) { ps += red[0][w][sl2][j2]; cs += red[1][w][sl2][j2]; }
    atomicAdd(&accum[sl2 * 16 + j2], ps);
    atomicAdd(&accum[64 + sl2 * 16 + j2], cs);
  }
}

__global__ void router_loss_kernel(const float* __restrict__ accum,
                                   float* __restrict__ out) {
  const int l = threadIdx.x;  // 64 threads
  float term = accum[l] * accum[64 + l];   // P_sum_e * count_e
#pragma unroll
  for (int m = 1; m < 64; m <<= 1) term += __shfl_xor(term, m, 64);
  if (l == 0) {
    const float invN = 1.f / (float)TOKENS;
    out[(size_t)TOKENS * 4] = 0.01f * 64.f * term * invN * invN;
  }
}

extern "C" void kernel_launch(void* const* d_in, const int* in_sizes, int n_in,
                              void* d_out, int out_size, void* d_ws, size_t ws_size,
                              hipStream_t stream) {
  const float* hidden = (const float*)d_in[0];  // [4,4096,4096] f32
  const float* gate   = (const float*)d_in[1];  // [64,4096] f32
  float* out   = (float*)d_out;                 // 32768 w + 32768 idx + 1 loss

  float* accum = (float*)d_ws;                                   // 128 f32
  float* pw    = (float*)((char*)d_ws + 1024);                   // 33.5 MB partials

  router_gemm_kernel<<<(TOKENS / 256) * NPARTS, 512, 0, stream>>>(hidden, gate, pw, accum);
  router_top2_kernel<<<TOKENS / 64, 256, 0, stream>>>(pw, out, accum);
  router_loss_kernel<<<1, 64, 0, stream>>>(accum, out);
}